// Round 14
// baseline (195.842 us; speedup 1.0000x reference)
//
#include <hip/hip_runtime.h>
#include <hip/hip_bf16.h>
#include <hip/hip_fp16.h>

#define S_LEN 4096
#define B_N   32
#define H_N   512
#define BH    (B_N * H_N)        // 16384
#define CROWS 64                 // s-rows per fused block
#define NCH   (S_LEN / CROWS)    // 64 chunks per b

typedef __attribute__((ext_vector_type(8))) short bf16x8;
typedef __attribute__((ext_vector_type(4))) float f32x4;

union bfu { __hip_bfloat162 h; unsigned u; };
__device__ __forceinline__ unsigned pk2(float a, float b) {
    bfu x; x.h = __float22bfloat162_rn(make_float2(a, b));  // v_cvt_pk_bf16_f32 (RNE)
    return x.u;
}

// async global->LDS: per-lane 16B from g (lane addr) to lds[base + lane*16]
__device__ __forceinline__ void gload_lds16(const void* g, void* l) {
    __builtin_amdgcn_global_load_lds(
        (__attribute__((address_space(1))) void*)g,
        (__attribute__((address_space(3))) void*)l, 16, 0, 0);
}

// ---------------- K1: prep = hsum (blocks 0..511) + wkfrag (blocks 512..639) ----------------
// wkfrag: WbF slot = ((wn*16 + ks)*4 + n)*64 + lane ; element j:
// col = wn*64 + n*16 + (lane&15), k = ks*32 + (lane>>4)*8 + j  (8-wn fragment order).
__global__ __launch_bounds__(256) void prep_kernel(const float* __restrict__ hs,
                                                   float* __restrict__ hsum,
                                                   const float* __restrict__ Wk,
                                                   unsigned short* __restrict__ WbF) {
    int bid = blockIdx.x, t = threadIdx.x;
    if (bid < 512) {                       // ---- hsum part ----
        int col = ((bid & 15) * 256 + t) * 4;
        size_t s0 = (size_t)(bid >> 4) * 128;
        float4 acc = {0.f, 0.f, 0.f, 0.f};
        #pragma unroll 8
        for (int i = 0; i < 128; ++i) {
            float4 v = *(const float4*)(hs + (s0 + i) * BH + col);
            acc.x += v.x; acc.y += v.y; acc.z += v.z; acc.w += v.w;
        }
        atomicAdd(&hsum[col],     acc.x);
        atomicAdd(&hsum[col + 1], acc.y);
        atomicAdd(&hsum[col + 2], acc.z);
        atomicAdd(&hsum[col + 3], acc.w);
    } else {                               // ---- wkfrag part ----
        int slot = (bid - 512) * 256 + t;  // 0..32767
        int lane = slot & 63;
        int n    = (slot >> 6) & 3;
        int ks   = (slot >> 8) & 15;
        int wn   = slot >> 12;
        int col = wn * 64 + n * 16 + (lane & 15);
        int k   = ks * 32 + (lane >> 4) * 8;
        const float* src = Wk + (size_t)col * H_N + k;
        float4 v0 = *(const float4*)(src);
        float4 v1 = *(const float4*)(src + 4);
        uint4 u4 = { pk2(v0.x, v0.y), pk2(v0.z, v0.w),
                     pk2(v1.x, v1.y), pk2(v1.z, v1.w) };
        *(uint4*)(WbF + (size_t)slot * 8) = u4;
    }
}

// ---------------- K2: q[b,h] — coalesced k-split, 8 blocks per b ----------------
__global__ __launch_bounds__(512) void q_kernel(const float* __restrict__ hsum,
                                                const float* __restrict__ Wq,
                                                const float* __restrict__ bq,
                                                float* __restrict__ q) {
    int b = blockIdx.x, part = blockIdx.y, t = threadIdx.x;
    int lane = t & 63, wv = t >> 6;
    __shared__ float hrow[H_N];
    hrow[t] = hsum[b * H_N + t] * (1.f / S_LEN);
    __syncthreads();
    float h0 = hrow[lane * 8 + 0], h1 = hrow[lane * 8 + 1];
    float h2 = hrow[lane * 8 + 2], h3 = hrow[lane * 8 + 3];
    float h4 = hrow[lane * 8 + 4], h5 = hrow[lane * 8 + 5];
    float h6 = hrow[lane * 8 + 6], h7 = hrow[lane * 8 + 7];
    #pragma unroll
    for (int j = 0; j < 8; ++j) {
        int h = part * 64 + wv * 8 + j;
        const float* wrow = Wq + (size_t)h * H_N + lane * 8;
        float4 w0 = *(const float4*)(wrow);
        float4 w1 = *(const float4*)(wrow + 4);
        float acc = h0 * w0.x + h1 * w0.y + h2 * w0.z + h3 * w0.w
                  + h4 * w1.x + h5 * w1.y + h6 * w1.z + h7 * w1.w;
        acc += __shfl_xor(acc, 1);  acc += __shfl_xor(acc, 2);
        acc += __shfl_xor(acc, 4);  acc += __shfl_xor(acc, 8);
        acc += __shfl_xor(acc, 16); acc += __shfl_xor(acc, 32);
        if (lane == 0) q[b * H_N + h] = acc + bq[h];
    }
}

// ---------------- K3: fused key GEMM + tanh + scores + softmax + PV ----------------
// 512 thr = 8 waves, wave wn owns cols wn*64..+63, all 64 rows (acc[4][4]).
// B streamed via wave-private async global_load_lds double-buffer:
// counted vmcnt, NO barriers in the K-loop.
__global__ __launch_bounds__(512, 2) void fused_kernel(
    const float* __restrict__ hs, const unsigned short* __restrict__ WbF,
    const float* __restrict__ bk, const float* __restrict__ qv,
    const int* __restrict__ lengths,
    float* __restrict__ pm, float* __restrict__ pl, float* __restrict__ po)
{
    int blk = blockIdx.x;
    int b = blk & 31;
    int chunk = blk >> 5;
    int s0 = chunk * CROWS;
    int t = threadIdx.x;

    int len = lengths[b];
    if (s0 >= len) {                       // fully masked: only pm sentinel needed
        if (t == 0) pm[b * NCH + chunk] = -1e30f;
        return;
    }

    int lane = t & 63, wn = t >> 6;
    int l15 = lane & 15, lg = lane >> 4;

    __shared__ __align__(16) unsigned short A_s[CROWS * H_N];   // 64 KB
    __shared__ __align__(16) unsigned short Bls[8 * 2 * 2048];  // 64 KB: [wave][slot][4KB]
    __shared__ float q_s[H_N];
    __shared__ float bk_s[H_N];
    __shared__ float scp[8][CROWS];
    __shared__ float p_s[CROWS];

    // wave-private B staging pointers (byte arithmetic)
    const char* wbW = (const char*)WbF + (size_t)wn * 65536 + lane * 16;
    char* blsW = (char*)Bls + wn * 8192;

    // prologue: issue B prefetch for ks=0,1 (hides under A staging below)
    #pragma unroll
    for (int n = 0; n < 4; ++n)
        gload_lds16(wbW + 0 * 4096 + n * 1024, blsW + 0 * 4096 + n * 1024);
    #pragma unroll
    for (int n = 0; n < 4; ++n)
        gload_lds16(wbW + 1 * 4096 + n * 1024, blsW + 1 * 4096 + n * 1024);

    q_s[t]  = qv[b * H_N + t];
    bk_s[t] = bk[t];

    // ---- stage A: 64 rows x 512 cols fp32 -> bf16 (packed cvt), swizzled ----
    const float* hb = hs + ((size_t)s0 * B_N + b) * H_N;   // row stride BH floats
    int kq  = t & 127;
    int r0l = t >> 7;
    #pragma unroll 8
    for (int j = 0; j < 16; ++j) {
        int row = r0l + 4 * j;
        float4 v = *(const float4*)(hb + (size_t)row * BH + kq * 4);
        uint2 u2 = { pk2(v.x, v.y), pk2(v.z, v.w) };
        *(uint2*)((char*)A_s + row * 1024 + ((kq * 8) ^ ((row & 7) << 4))) = u2;
    }
    __syncthreads();   // drains A loads (and the prologue prefetch: it has landed)

    // ---- K-loop: 16 steps; wave-private B dbuf, counted vmcnt, no barriers ----
    const char* Ab = (const char*)A_s + l15 * 1024;
    int axor = (l15 & 7) << 4;

    f32x4 acc[4][4];
    #pragma unroll
    for (int m = 0; m < 4; ++m)
        #pragma unroll
        for (int n = 0; n < 4; ++n) acc[m][n] = (f32x4){0.f, 0.f, 0.f, 0.f};

    #pragma unroll
    for (int ks = 0; ks < 16; ++ks) {
        if (ks == 15) asm volatile("s_waitcnt vmcnt(0)" ::: "memory");
        else          asm volatile("s_waitcnt vmcnt(4)" ::: "memory");
        const char* bb = blsW + (ks & 1) * 4096 + lane * 16;
        bf16x8 b0 = *(const bf16x8*)(bb + 0 * 1024);
        bf16x8 b1 = *(const bf16x8*)(bb + 1 * 1024);
        bf16x8 b2 = *(const bf16x8*)(bb + 2 * 1024);
        bf16x8 b3 = *(const bf16x8*)(bb + 3 * 1024);
        int off = (ks * 64 + lg * 16) ^ axor;
        bf16x8 a0 = *(const bf16x8*)(Ab + off);
        bf16x8 a1 = *(const bf16x8*)(Ab + 16 * 1024 + off);
        bf16x8 a2 = *(const bf16x8*)(Ab + 32 * 1024 + off);
        bf16x8 a3 = *(const bf16x8*)(Ab + 48 * 1024 + off);
        asm volatile("s_waitcnt lgkmcnt(0)" ::: "memory");   // ds data in regs before slot reuse
        if (ks + 2 < 16) {
            #pragma unroll
            for (int n = 0; n < 4; ++n)
                gload_lds16(wbW + (ks + 2) * 4096 + n * 1024,
                            blsW + (ks & 1) * 4096 + n * 1024);
        }
        acc[0][0] = __builtin_amdgcn_mfma_f32_16x16x32_bf16(a0, b0, acc[0][0], 0, 0, 0);
        acc[1][0] = __builtin_amdgcn_mfma_f32_16x16x32_bf16(a1, b0, acc[1][0], 0, 0, 0);
        acc[2][0] = __builtin_amdgcn_mfma_f32_16x16x32_bf16(a2, b0, acc[2][0], 0, 0, 0);
        acc[3][0] = __builtin_amdgcn_mfma_f32_16x16x32_bf16(a3, b0, acc[3][0], 0, 0, 0);
        acc[0][1] = __builtin_amdgcn_mfma_f32_16x16x32_bf16(a0, b1, acc[0][1], 0, 0, 0);
        acc[1][1] = __builtin_amdgcn_mfma_f32_16x16x32_bf16(a1, b1, acc[1][1], 0, 0, 0);
        acc[2][1] = __builtin_amdgcn_mfma_f32_16x16x32_bf16(a2, b1, acc[2][1], 0, 0, 0);
        acc[3][1] = __builtin_amdgcn_mfma_f32_16x16x32_bf16(a3, b1, acc[3][1], 0, 0, 0);
        acc[0][2] = __builtin_amdgcn_mfma_f32_16x16x32_bf16(a0, b2, acc[0][2], 0, 0, 0);
        acc[1][2] = __builtin_amdgcn_mfma_f32_16x16x32_bf16(a1, b2, acc[1][2], 0, 0, 0);
        acc[2][2] = __builtin_amdgcn_mfma_f32_16x16x32_bf16(a2, b2, acc[2][2], 0, 0, 0);
        acc[3][2] = __builtin_amdgcn_mfma_f32_16x16x32_bf16(a3, b2, acc[3][2], 0, 0, 0);
        acc[0][3] = __builtin_amdgcn_mfma_f32_16x16x32_bf16(a0, b3, acc[0][3], 0, 0, 0);
        acc[1][3] = __builtin_amdgcn_mfma_f32_16x16x32_bf16(a1, b3, acc[1][3], 0, 0, 0);
        acc[2][3] = __builtin_amdgcn_mfma_f32_16x16x32_bf16(a2, b3, acc[2][3], 0, 0, 0);
        acc[3][3] = __builtin_amdgcn_mfma_f32_16x16x32_bf16(a3, b3, acc[3][3], 0, 0, 0);
    }

    // ---- epilogue: bias + tanh (v_rcp) + score partials ----
    // C/D: lane holds D[row = m*16 + lg*4 + i][col = wn*64 + n*16 + l15]
    float sp[4][4] = {{0,0,0,0},{0,0,0,0},{0,0,0,0},{0,0,0,0}};
    #pragma unroll
    for (int m = 0; m < 4; ++m)
        #pragma unroll
        for (int n = 0; n < 4; ++n) {
            int c = wn * 64 + n * 16 + l15;
            float bkv = bk_s[c], qc = q_s[c];
            #pragma unroll
            for (int i = 0; i < 4; ++i) {
                float z = acc[m][n][i] + bkv;
                float e = __expf(2.f * z);
                float kv = 1.f - 2.f * __builtin_amdgcn_rcpf(e + 1.f);  // tanh
                acc[m][n][i] = kv;                                      // key in regs
                sp[m][i] = fmaf(kv, qc, sp[m][i]);
            }
        }
    #pragma unroll
    for (int m = 0; m < 4; ++m)
        #pragma unroll
        for (int i = 0; i < 4; ++i) {
            float v = sp[m][i];
            v += __shfl_xor(v, 1); v += __shfl_xor(v, 2);
            v += __shfl_xor(v, 4); v += __shfl_xor(v, 8);
            if (l15 == 0) scp[wn][m * 16 + lg * 4 + i] = v;
        }
    __syncthreads();

    // ---- softmax: lane owns row=lane; wave-parallel max/sum ----
    {
        float sc = 0.f;
        #pragma unroll
        for (int w = 0; w < 8; ++w) sc += scp[w][lane];
        if (s0 + lane >= len) sc -= 10000.f;
        float mx = sc;
        #pragma unroll
        for (int d = 1; d < 64; d <<= 1) mx = fmaxf(mx, __shfl_xor(mx, d));
        float p = __expf(sc - mx);
        if (wn == 0) {
            p_s[lane] = p;
            float l = p;
            #pragma unroll
            for (int d = 1; d < 64; d <<= 1) l += __shfl_xor(l, d);
            if (lane == 0) { pm[b * NCH + chunk] = mx; pl[b * NCH + chunk] = l; }
        }
    }
    __syncthreads();

    // ---- PV: wave-local; reduce across lg ----
    float o4[4] = {0, 0, 0, 0};
    #pragma unroll
    for (int m = 0; m < 4; ++m)
        #pragma unroll
        for (int i = 0; i < 4; ++i) {
            float p = p_s[m * 16 + lg * 4 + i];
            #pragma unroll
            for (int n = 0; n < 4; ++n) o4[n] = fmaf(p, acc[m][n][i], o4[n]);
        }
    #pragma unroll
    for (int n = 0; n < 4; ++n) {
        float v = o4[n];
        v += __shfl_xor(v, 16);
        v += __shfl_xor(v, 32);
        o4[n] = v;
    }
    if (lg == 0) {
        float* pob = po + ((size_t)b * NCH + chunk) * H_N + wn * 64 + l15;
        #pragma unroll
        for (int n = 0; n < 4; ++n) pob[n * 16] = o4[n];
    }
}

// ---------------- K4: combine chunk partials — branchless, 1 col/thread ----------------
// Masked chunks: pm = -1e30 -> w = expf(-1e30 - M) == 0 exactly; 0xAA poison in
// pl/po is -3.03e-13 (not NaN), so fmaf(0, poison, acc) == acc. No guard needed.
__global__ __launch_bounds__(512) void combine_kernel(
    const float* __restrict__ pm, const float* __restrict__ pl,
    const float* __restrict__ po, float* __restrict__ out)
{
    int b = blockIdx.x, t = threadIdx.x;   // t = column 0..511
    float M = -1e30f;
    #pragma unroll 8
    for (int c = 0; c < NCH; ++c) M = fmaxf(M, pm[b * NCH + c]);
    float den = 0.f, n0 = 0.f;
    #pragma unroll 8
    for (int c = 0; c < NCH; ++c) {
        float w = __expf(pm[b * NCH + c] - M);
        den = fmaf(w, pl[b * NCH + c], den);
        n0  = fmaf(w, po[(size_t)(b * NCH + c) * H_N + t], n0);
    }
    out[b * H_N + t] = n0 / den;
}

extern "C" void kernel_launch(void* const* d_in, const int* in_sizes, int n_in,
                              void* d_out, int out_size, void* d_ws, size_t ws_size,
                              hipStream_t stream) {
    const float* hs      = (const float*)d_in[0];
    const float* Wq      = (const float*)d_in[1];
    const float* bq      = (const float*)d_in[2];
    const float* Wk      = (const float*)d_in[3];
    const float* bk      = (const float*)d_in[4];
    const int*   lengths = (const int*)d_in[5];
    float* out = (float*)d_out;

    float* ws   = (float*)d_ws;
    float* hsum = ws;                              // 16384 floats
    float* qv   = hsum + BH;                       // 16384
    float* pm   = qv + BH;                         // 2048
    float* pl   = pm + B_N * NCH;                  // 2048
    float* po   = pl + B_N * NCH;                  // 1048576 floats
    unsigned short* WbF = (unsigned short*)(po + (size_t)B_N * NCH * H_N); // 512 KB

    hipMemsetAsync(hsum, 0, BH * sizeof(float), stream);
    hipLaunchKernelGGL(prep_kernel, dim3(640), dim3(256), 0, stream, hs, hsum, Wk, (unsigned short*)WbF);
    hipLaunchKernelGGL(q_kernel, dim3(B_N, 8), dim3(512), 0, stream, hsum, Wq, bq, qv);
    hipLaunchKernelGGL(fused_kernel, dim3(B_N * NCH), dim3(512), 0, stream,
                       hs, WbF, bk, qv, lengths, pm, pl, po);
    hipLaunchKernelGGL(combine_kernel, dim3(B_N), dim3(512), 0, stream, pm, pl, po, out);
}

// Round 15
// 181.752 us; speedup vs baseline: 1.0775x; 1.0775x over previous
//
#include <hip/hip_runtime.h>
#include <hip/hip_bf16.h>
#include <hip/hip_fp16.h>

#define S_LEN 4096
#define B_N   32
#define H_N   512
#define BH    (B_N * H_N)        // 16384
#define CROWS 64                 // s-rows per block
#define NCH   (S_LEN / CROWS)    // 64 chunks per b

typedef __attribute__((ext_vector_type(8))) short bf16x8;
typedef __attribute__((ext_vector_type(4))) float f32x4;

union bfu { __hip_bfloat162 h; unsigned u; };
__device__ __forceinline__ unsigned pk2(float a, float b) {
    bfu x; x.h = __float22bfloat162_rn(make_float2(a, b));  // v_cvt_pk_bf16_f32
    return x.u;
}
union hfu { __half2 h; unsigned u; };
__device__ __forceinline__ unsigned pkh(float a, float b) {
    hfu x; x.h = __floats2half2_rn(a, b);                   // v_cvt_pk f16
    return x.u;
}
__device__ __forceinline__ float2 uph(unsigned u) {
    hfu x; x.u = u; return __half22float2(x.h);
}

// ---------------- K0: Wk fp32 -> bf16 fragment order (8-wn split) ----------------
// slot = ((wn*16+ks)*4+n)*64+lane ; elem j: col = wn*64+n*16+(lane&15),
// k = ks*32+(lane>>4)*8+j. Wave B-load = 1KB contiguous.
__global__ __launch_bounds__(256) void wkfrag_kernel(const float* __restrict__ Wk,
                                                     unsigned short* __restrict__ WbF) {
    int slot = blockIdx.x * 256 + threadIdx.x;
    int lane = slot & 63;
    int n    = (slot >> 6) & 3;
    int ks   = (slot >> 8) & 15;
    int wn   = slot >> 12;
    int col = wn * 64 + n * 16 + (lane & 15);
    int k   = ks * 32 + (lane >> 4) * 8;
    const float* src = Wk + (size_t)col * H_N + k;
    float4 v0 = *(const float4*)(src);
    float4 v1 = *(const float4*)(src + 4);
    uint4 u4 = { pk2(v0.x, v0.y), pk2(v0.z, v0.w),
                 pk2(v1.x, v1.y), pk2(v1.z, v1.w) };
    *(uint4*)(WbF + (size_t)slot * 8) = u4;
}

// ---------------- K1: pass1 = hsum fold + key GEMM + tanh + fp16 key store ----------------
// Block (b,chunk). hs read exactly once per tile; masked chunks exit after hsum.
__global__ __launch_bounds__(512, 4) void gemm_kernel(
    const float* __restrict__ hs, const unsigned short* __restrict__ WbF,
    const float* __restrict__ bk, const int* __restrict__ lengths,
    float* __restrict__ hsum, unsigned* __restrict__ keyw)
{
    int blk = blockIdx.x;
    int b = blk & 31;
    int chunk = blk >> 5;
    int s0 = chunk * CROWS;
    int t = threadIdx.x;
    int len = lengths[b];
    bool active = (s0 < len);

    int lane = t & 63, wn = t >> 6;
    int l15 = lane & 15, lg = lane >> 4;

    __shared__ __align__(16) unsigned short A_s[CROWS * H_N]; // 64 KB
    __shared__ float hsred[4][H_N];                           // 8 KB
    __shared__ float bk_s[H_N];

    bk_s[t] = bk[t];

    // ---- stage A (fp32->bf16 swizzled) + column-sum fold ----
    const float* hb = hs + ((size_t)s0 * B_N + b) * H_N;
    int kq  = t & 127;
    int r0l = t >> 7;
    float4 cs = {0.f, 0.f, 0.f, 0.f};
    #pragma unroll 8
    for (int j = 0; j < 16; ++j) {
        int row = r0l + 4 * j;
        float4 v = *(const float4*)(hb + (size_t)row * BH + kq * 4);
        cs.x += v.x; cs.y += v.y; cs.z += v.z; cs.w += v.w;
        if (active) {
            uint2 u2 = { pk2(v.x, v.y), pk2(v.z, v.w) };
            *(uint2*)((char*)A_s + row * 1024 + ((kq * 8) ^ ((row & 7) << 4))) = u2;
        }
    }
    *(float4*)&hsred[r0l][kq * 4] = cs;
    __syncthreads();
    {
        float s = hsred[0][t] + hsred[1][t] + hsred[2][t] + hsred[3][t];
        atomicAdd(&hsum[b * H_N + t], s);
    }
    if (!active) return;

    // ---- K-loop (R13 exact): 16 steps, 4 B + 4 A frags, 16 MFMA ----
    const unsigned short* wbF = WbF + (size_t)wn * 32768 + lane * 8;
    const char* Ab = (const char*)A_s + l15 * 1024;
    int axor = (l15 & 7) << 4;

    f32x4 acc[4][4];
    #pragma unroll
    for (int m = 0; m < 4; ++m)
        #pragma unroll
        for (int n = 0; n < 4; ++n) acc[m][n] = (f32x4){0.f, 0.f, 0.f, 0.f};

    #pragma unroll
    for (int ks = 0; ks < 16; ++ks) {
        const unsigned short* wk = wbF + ks * 2048;
        bf16x8 b0 = *(const bf16x8*)(wk + 0 * 512);
        bf16x8 b1 = *(const bf16x8*)(wk + 1 * 512);
        bf16x8 b2 = *(const bf16x8*)(wk + 2 * 512);
        bf16x8 b3 = *(const bf16x8*)(wk + 3 * 512);
        int off = (ks * 64 + lg * 16) ^ axor;
        bf16x8 a0 = *(const bf16x8*)(Ab + off);
        bf16x8 a1 = *(const bf16x8*)(Ab + 16 * 1024 + off);
        bf16x8 a2 = *(const bf16x8*)(Ab + 32 * 1024 + off);
        bf16x8 a3 = *(const bf16x8*)(Ab + 48 * 1024 + off);
        acc[0][0] = __builtin_amdgcn_mfma_f32_16x16x32_bf16(a0, b0, acc[0][0], 0, 0, 0);
        acc[1][0] = __builtin_amdgcn_mfma_f32_16x16x32_bf16(a1, b0, acc[1][0], 0, 0, 0);
        acc[2][0] = __builtin_amdgcn_mfma_f32_16x16x32_bf16(a2, b0, acc[2][0], 0, 0, 0);
        acc[3][0] = __builtin_amdgcn_mfma_f32_16x16x32_bf16(a3, b0, acc[3][0], 0, 0, 0);
        acc[0][1] = __builtin_amdgcn_mfma_f32_16x16x32_bf16(a0, b1, acc[0][1], 0, 0, 0);
        acc[1][1] = __builtin_amdgcn_mfma_f32_16x16x32_bf16(a1, b1, acc[1][1], 0, 0, 0);
        acc[2][1] = __builtin_amdgcn_mfma_f32_16x16x32_bf16(a2, b1, acc[2][1], 0, 0, 0);
        acc[3][1] = __builtin_amdgcn_mfma_f32_16x16x32_bf16(a3, b1, acc[3][1], 0, 0, 0);
        acc[0][2] = __builtin_amdgcn_mfma_f32_16x16x32_bf16(a0, b2, acc[0][2], 0, 0, 0);
        acc[1][2] = __builtin_amdgcn_mfma_f32_16x16x32_bf16(a1, b2, acc[1][2], 0, 0, 0);
        acc[2][2] = __builtin_amdgcn_mfma_f32_16x16x32_bf16(a2, b2, acc[2][2], 0, 0, 0);
        acc[3][2] = __builtin_amdgcn_mfma_f32_16x16x32_bf16(a3, b2, acc[3][2], 0, 0, 0);
        acc[0][3] = __builtin_amdgcn_mfma_f32_16x16x32_bf16(a0, b3, acc[0][3], 0, 0, 0);
        acc[1][3] = __builtin_amdgcn_mfma_f32_16x16x32_bf16(a1, b3, acc[1][3], 0, 0, 0);
        acc[2][3] = __builtin_amdgcn_mfma_f32_16x16x32_bf16(a2, b3, acc[2][3], 0, 0, 0);
        acc[3][3] = __builtin_amdgcn_mfma_f32_16x16x32_bf16(a3, b3, acc[3][3], 0, 0, 0);
    }

    // ---- epilogue: bias + tanh (v_rcp) + pack fp16 + thread-linear store ----
    unsigned kw[32];
    #pragma unroll
    for (int m = 0; m < 4; ++m)
        #pragma unroll
        for (int n = 0; n < 4; ++n) {
            float bkv = bk_s[wn * 64 + n * 16 + l15];
            float kv[4];
            #pragma unroll
            for (int i = 0; i < 4; ++i) {
                float z = acc[m][n][i] + bkv;
                float e = __expf(2.f * z);
                kv[i] = 1.f - 2.f * __builtin_amdgcn_rcpf(e + 1.f);   // tanh
            }
            kw[(m * 4 + n) * 2 + 0] = pkh(kv[0], kv[1]);
            kw[(m * 4 + n) * 2 + 1] = pkh(kv[2], kv[3]);
        }
    uint4* dst = (uint4*)(keyw + (size_t)blk * 16384 + t * 32);
    #pragma unroll
    for (int j = 0; j < 8; ++j) dst[j] = ((uint4*)kw)[j];
}

// ---------------- K2: q[b,h] — coalesced k-split, 8 blocks per b ----------------
__global__ __launch_bounds__(512) void q_kernel(const float* __restrict__ hsum,
                                                const float* __restrict__ Wq,
                                                const float* __restrict__ bq,
                                                float* __restrict__ q) {
    int b = blockIdx.x, part = blockIdx.y, t = threadIdx.x;
    int lane = t & 63, wv = t >> 6;
    __shared__ float hrow[H_N];
    hrow[t] = hsum[b * H_N + t] * (1.f / S_LEN);
    __syncthreads();
    float h0 = hrow[lane * 8 + 0], h1 = hrow[lane * 8 + 1];
    float h2 = hrow[lane * 8 + 2], h3 = hrow[lane * 8 + 3];
    float h4 = hrow[lane * 8 + 4], h5 = hrow[lane * 8 + 5];
    float h6 = hrow[lane * 8 + 6], h7 = hrow[lane * 8 + 7];
    #pragma unroll
    for (int j = 0; j < 8; ++j) {
        int h = part * 64 + wv * 8 + j;
        const float* wrow = Wq + (size_t)h * H_N + lane * 8;
        float4 w0 = *(const float4*)(wrow);
        float4 w1 = *(const float4*)(wrow + 4);
        float acc = h0 * w0.x + h1 * w0.y + h2 * w0.z + h3 * w0.w
                  + h4 * w1.x + h5 * w1.y + h6 * w1.z + h7 * w1.w;
        acc += __shfl_xor(acc, 1);  acc += __shfl_xor(acc, 2);
        acc += __shfl_xor(acc, 4);  acc += __shfl_xor(acc, 8);
        acc += __shfl_xor(acc, 16); acc += __shfl_xor(acc, 32);
        if (lane == 0) q[b * H_N + h] = acc + bq[h];
    }
}

// ---------------- K3: pass2 = scores + softmax + PV from stored fp16 key ----------------
// Same thread geometry as pass1's store -> thread reloads its own 64 values.
__global__ __launch_bounds__(512, 4) void score_kernel(
    const unsigned* __restrict__ keyw, const float* __restrict__ qv,
    const int* __restrict__ lengths,
    float* __restrict__ pm, float* __restrict__ pl, float* __restrict__ po)
{
    int blk = blockIdx.x;
    int b = blk & 31;
    int chunk = blk >> 5;
    int s0 = chunk * CROWS;
    int t = threadIdx.x;
    int len = lengths[b];
    if (s0 >= len) {
        if (t == 0) pm[b * NCH + chunk] = -1e30f;
        return;
    }
    int lane = t & 63, wn = t >> 6;
    int l15 = lane & 15, lg = lane >> 4;

    __shared__ float q_s[H_N];
    __shared__ float scp[8][CROWS];
    __shared__ float p_s[CROWS];

    q_s[t] = qv[b * H_N + t];

    // reload my key values (coalesced 128B/thread)
    unsigned kw[32];
    const uint4* src = (const uint4*)(keyw + (size_t)blk * 16384 + t * 32);
    #pragma unroll
    for (int j = 0; j < 8; ++j) ((uint4*)kw)[j] = src[j];
    float kvf[4][4][4];
    #pragma unroll
    for (int m = 0; m < 4; ++m)
        #pragma unroll
        for (int n = 0; n < 4; ++n) {
            float2 f01 = uph(kw[(m * 4 + n) * 2 + 0]);
            float2 f23 = uph(kw[(m * 4 + n) * 2 + 1]);
            kvf[m][n][0] = f01.x; kvf[m][n][1] = f01.y;
            kvf[m][n][2] = f23.x; kvf[m][n][3] = f23.y;
        }
    __syncthreads();   // q_s ready

    // ---- scores (R13 epilogue layout): row = m*16+lg*4+i, col = wn*64+n*16+l15 ----
    float sp[4][4] = {{0,0,0,0},{0,0,0,0},{0,0,0,0},{0,0,0,0}};
    #pragma unroll
    for (int m = 0; m < 4; ++m)
        #pragma unroll
        for (int n = 0; n < 4; ++n) {
            float qc = q_s[wn * 64 + n * 16 + l15];
            #pragma unroll
            for (int i = 0; i < 4; ++i)
                sp[m][i] = fmaf(kvf[m][n][i], qc, sp[m][i]);
        }
    #pragma unroll
    for (int m = 0; m < 4; ++m)
        #pragma unroll
        for (int i = 0; i < 4; ++i) {
            float v = sp[m][i];
            v += __shfl_xor(v, 1); v += __shfl_xor(v, 2);
            v += __shfl_xor(v, 4); v += __shfl_xor(v, 8);
            if (l15 == 0) scp[wn][m * 16 + lg * 4 + i] = v;
        }
    __syncthreads();

    // ---- softmax: lane owns row=lane; wave-parallel ----
    {
        float sc = 0.f;
        #pragma unroll
        for (int w = 0; w < 8; ++w) sc += scp[w][lane];
        if (s0 + lane >= len) sc -= 10000.f;
        float mx = sc;
        #pragma unroll
        for (int d = 1; d < 64; d <<= 1) mx = fmaxf(mx, __shfl_xor(mx, d));
        float p = __expf(sc - mx);
        if (wn == 0) {
            p_s[lane] = p;
            float l = p;
            #pragma unroll
            for (int d = 1; d < 64; d <<= 1) l += __shfl_xor(l, d);
            if (lane == 0) { pm[b * NCH + chunk] = mx; pl[b * NCH + chunk] = l; }
        }
    }
    __syncthreads();

    // ---- PV ----
    float o4[4] = {0, 0, 0, 0};
    #pragma unroll
    for (int m = 0; m < 4; ++m)
        #pragma unroll
        for (int i = 0; i < 4; ++i) {
            float p = p_s[m * 16 + lg * 4 + i];
            #pragma unroll
            for (int n = 0; n < 4; ++n) o4[n] = fmaf(p, kvf[m][n][i], o4[n]);
        }
    #pragma unroll
    for (int n = 0; n < 4; ++n) {
        float v = o4[n];
        v += __shfl_xor(v, 16);
        v += __shfl_xor(v, 32);
        o4[n] = v;
    }
    if (lg == 0) {
        float* pob = po + ((size_t)b * NCH + chunk) * H_N + wn * 64 + l15;
        #pragma unroll
        for (int n = 0; n < 4; ++n) pob[n * 16] = o4[n];
    }
}

// ---------------- K4: combine chunk partials — branchless ----------------
__global__ __launch_bounds__(512) void combine_kernel(
    const float* __restrict__ pm, const float* __restrict__ pl,
    const float* __restrict__ po, float* __restrict__ out)
{
    int b = blockIdx.x, t = threadIdx.x;
    float M = -1e30f;
    #pragma unroll 8
    for (int c = 0; c < NCH; ++c) M = fmaxf(M, pm[b * NCH + c]);
    float den = 0.f, n0 = 0.f;
    #pragma unroll 8
    for (int c = 0; c < NCH; ++c) {
        float w = __expf(pm[b * NCH + c] - M);
        den = fmaf(w, pl[b * NCH + c], den);
        n0  = fmaf(w, po[(size_t)(b * NCH + c) * H_N + t], n0);
    }
    out[b * H_N + t] = n0 / den;
}

extern "C" void kernel_launch(void* const* d_in, const int* in_sizes, int n_in,
                              void* d_out, int out_size, void* d_ws, size_t ws_size,
                              hipStream_t stream) {
    const float* hs      = (const float*)d_in[0];
    const float* Wq      = (const float*)d_in[1];
    const float* bq      = (const float*)d_in[2];
    const float* Wk      = (const float*)d_in[3];
    const float* bk      = (const float*)d_in[4];
    const int*   lengths = (const int*)d_in[5];
    float* out = (float*)d_out;

    float* ws   = (float*)d_ws;
    float* hsum = ws;                              // 16384 floats
    float* qv   = hsum + BH;                       // 16384
    float* pm   = qv + BH;                         // 2048
    float* pl   = pm + B_N * NCH;                  // 2048
    float* po   = pl + B_N * NCH;                  // 1048576 floats
    unsigned short* WbF = (unsigned short*)(po + (size_t)B_N * NCH * H_N); // 512 KB
    unsigned* keyw = (unsigned*)(WbF + (size_t)H_N * H_N);                 // 128 MiB

    hipMemsetAsync(hsum, 0, BH * sizeof(float), stream);
    hipLaunchKernelGGL(wkfrag_kernel, dim3(128), dim3(256), 0, stream, Wk, WbF);
    hipLaunchKernelGGL(gemm_kernel, dim3(B_N * NCH), dim3(512), 0, stream,
                       hs, WbF, bk, lengths, hsum, keyw);
    hipLaunchKernelGGL(q_kernel, dim3(B_N, 8), dim3(512), 0, stream, hsum, Wq, bq, qv);
    hipLaunchKernelGGL(score_kernel, dim3(B_N * NCH), dim3(512), 0, stream,
                       keyw, qv, lengths, pm, pl, po);
    hipLaunchKernelGGL(combine_kernel, dim3(B_N), dim3(512), 0, stream, pm, pl, po, out);
}